// Round 4
// baseline (1257.917 us; speedup 1.0000x reference)
//
#include <hip/hip_runtime.h>

#define Bsz 16384
#define TT 10
#define FF 500
#define H1c 256
#define H2c 100

typedef _Float16 half8 __attribute__((ext_vector_type(8)));
typedef float floatx4 __attribute__((ext_vector_type(4)));

__device__ __forceinline__ float sigm(float x) { return 1.0f / (1.0f + __expf(-x)); }

#define GLOAD16(g, l) __builtin_amdgcn_global_load_lds( \
    (const __attribute__((address_space(1))) void*)(g), \
    (__attribute__((address_space(3))) void*)(l), 16, 0, 0)

// ---------------------------------------------------------------------------
// Convert ALL noise fp32 -> xc fp16 once; rows are flat (b*10+t), 500->512 pad.
// ---------------------------------------------------------------------------
__global__ __launch_bounds__(256)
void conv_all(const float* __restrict__ noise, _Float16* __restrict__ xc)
{
    const int idx = blockIdx.x * 256 + threadIdx.x;
    const int row = idx >> 6;
    const int kc = (idx & 63) << 3;
    const float* src = noise + (size_t)row * FF + kc;
    half8 v;
    if (kc + 8 <= FF) {
        float4 u0 = *(const float4*)src;
        float4 u1 = *(const float4*)(src + 4);
        v[0] = (_Float16)u0.x; v[1] = (_Float16)u0.y; v[2] = (_Float16)u0.z; v[3] = (_Float16)u0.w;
        v[4] = (_Float16)u1.x; v[5] = (_Float16)u1.y; v[6] = (_Float16)u1.z; v[7] = (_Float16)u1.w;
    } else {
        #pragma unroll
        for (int j = 0; j < 8; ++j)
            v[j] = (kc + j < FF) ? (_Float16)src[j] : (_Float16)0.f;
    }
    *(half8*)(xc + (size_t)row * 512 + kc) = v;
}

// ---------------------------------------------------------------------------
// LSTM weight prep (combined K=768): n' = 128*(U>>5)+64*((U>>4)&1)+16*g+(U&15)
// k<512: Wx rows (500 real, pad 0); k in [512,768): Wh rows.
// ---------------------------------------------------------------------------
__global__ __launch_bounds__(256)
void prep_lstm_w(const float* __restrict__ Wx, const float* __restrict__ Wh,
                 _Float16* __restrict__ WT)
{
    const int idx = blockIdx.x * 256 + threadIdx.x;   // 1024*768
    const int np = idx / 768, k = idx % 768;
    const int a = np >> 7, b2 = (np >> 6) & 1, g = (np >> 4) & 3, u = np & 15;
    const int U = a * 32 + b2 * 16 + u;
    const int col = g * 256 + U;
    float v = 0.f;
    if (k < 512) { if (k < FF) v = Wx[(size_t)k * 1024 + col]; }
    else v = Wh[(size_t)(k - 512) * 1024 + col];
    WT[idx] = (_Float16)v;
}

// ---------------------------------------------------------------------------
// GRU weight prep: n' = 96*(U>>5)+48*((U>>4)&1)+16*g+(U&15), U in [0,128).
// k<256: Wxg rows; k in [256,384): Whg rows (100 real).
// ---------------------------------------------------------------------------
__global__ __launch_bounds__(256)
void prep_gru_w(const float* __restrict__ Wxg, const float* __restrict__ Whg,
                _Float16* __restrict__ WT)
{
    const int idx = blockIdx.x * 256 + threadIdx.x;   // 384*384
    if (idx >= 384 * 384) return;
    const int np = idx / 384, k = idx % 384;
    const int nb = np / 96, rem = np % 96;
    const int wxx = rem / 48, g = (rem % 48) / 16, u = rem & 15;
    const int U = nb * 32 + wxx * 16 + u;
    float v = 0.f;
    if (U < H2c) {
        if (k < 256) v = Wxg[(size_t)k * 300 + g * H2c + U];
        else if (k - 256 < H2c) v = Whg[(size_t)(k - 256) * 300 + g * H2c + U];
    }
    WT[idx] = (_Float16)v;
}

// ---------------------------------------------------------------------------
// LSTM tile body: z = [x_t | h_prev] @ WT^T + b (K=768), fused gate epilogue.
// 128x128 tile, 4 waves, BK=32. bid in [0,1024), XCD-swizzled.
// ---------------------------------------------------------------------------
__device__ __forceinline__
void lstm_body(int bid, const _Float16* __restrict__ xc, const _Float16* __restrict__ WT,
               const float* __restrict__ bias,
               const _Float16* __restrict__ h_prev, const float* __restrict__ c_prev,
               _Float16* __restrict__ h_out, float* __restrict__ c_out,
               int t, int first, _Float16* As, _Float16* Bs)
{
    const int tid = threadIdx.x;
    const int lane = tid & 63;
    const int w = tid >> 6;
    const int wy = w >> 1, wx = w & 1;
    const int swz = (bid & 7) * 128 + (bid >> 3);
    const int row0 = (swz >> 3) * 128;
    const int nb = swz & 7;

    floatx4 acc[4][4];
    #pragma unroll
    for (int a = 0; a < 4; ++a)
        #pragma unroll
        for (int b = 0; b < 4; ++b) acc[a][b] = (floatx4){0.f, 0.f, 0.f, 0.f};

    const int slr = lane >> 2;
    const int slc = (lane & 3) * 8;
    const int fr = lane & 15;
    const int fk = (lane >> 4) * 8;

    const int nkt = first ? 16 : 24;
    for (int kt8 = 0; kt8 < nkt; ++kt8) {
        const int kb = kt8 * 32;
        #pragma unroll
        for (int i = 0; i < 2; ++i) {
            const int r = w * 32 + i * 16;
            GLOAD16(WT + (size_t)(nb * 128 + r + slr) * 768 + kb + slc, &Bs[r * 32]);
        }
        if (kt8 < 16) {
            #pragma unroll
            for (int i = 0; i < 2; ++i) {
                const int r = w * 32 + i * 16;
                GLOAD16(xc + ((size_t)(row0 + r + slr) * 10 + t) * 512 + kb + slc, &As[r * 32]);
            }
        } else {
            #pragma unroll
            for (int i = 0; i < 2; ++i) {
                const int r = w * 32 + i * 16;
                GLOAD16(h_prev + (size_t)(row0 + r + slr) * 256 + (kb - 512) + slc, &As[r * 32]);
            }
        }
        __syncthreads();
        half8 af[4], bf[4];
        #pragma unroll
        for (int mi = 0; mi < 4; ++mi)
            af[mi] = *(const half8*)&As[(wy * 64 + mi * 16 + fr) * 32 + fk];
        #pragma unroll
        for (int ni = 0; ni < 4; ++ni)
            bf[ni] = *(const half8*)&Bs[(wx * 64 + ni * 16 + fr) * 32 + fk];
        #pragma unroll
        for (int mi = 0; mi < 4; ++mi)
            #pragma unroll
            for (int ni = 0; ni < 4; ++ni)
                acc[mi][ni] = __builtin_amdgcn_mfma_f32_16x16x32_f16(af[mi], bf[ni], acc[mi][ni], 0, 0, 0);
        __syncthreads();
    }

    const int U = nb * 32 + wx * 16 + fr;
    const float bi = bias[0 * 256 + U];
    const float bff = bias[1 * 256 + U];
    const float bg = bias[2 * 256 + U];
    const float bo = bias[3 * 256 + U];
    const int rbase = row0 + wy * 64 + (lane >> 4) * 4;
    #pragma unroll
    for (int mi = 0; mi < 4; ++mi) {
        #pragma unroll
        for (int r = 0; r < 4; ++r) {
            const int row = rbase + mi * 16 + r;
            const float cp = first ? 0.f : c_prev[(size_t)row * 256 + U];
            const float zi = acc[mi][0][r] + bi;
            const float zf = acc[mi][1][r] + bff;
            const float zg = acc[mi][2][r] + bg;
            const float zo = acc[mi][3][r] + bo;
            const float ig = sigm(zi), fg = sigm(zf), og = sigm(zo);
            const float gg = fmaxf(zg, 0.f);
            const float cv = fg * cp + ig * gg;
            const float hv = og * fmaxf(cv, 0.f);
            c_out[(size_t)row * 256 + U] = cv;
            h_out[(size_t)row * 256 + U] = (_Float16)hv;
        }
    }
}

// ---------------------------------------------------------------------------
// GRU tile body: mx = h @ Wxg (K=256), mh = g_prev @ Whg (K=128 padded).
// 128x96 tile (3 gates x 32 units), 4 waves. bid2 in [0,512), XCD-swizzled.
// ---------------------------------------------------------------------------
__device__ __forceinline__
void gru_body(int bid2, const _Float16* __restrict__ hx, const _Float16* __restrict__ WT,
              const float* __restrict__ b_in, const float* __restrict__ b_rec,
              const float* __restrict__ g_prev, const _Float16* __restrict__ g16_prev,
              float* __restrict__ g_out, _Float16* __restrict__ g16_out,
              int first, _Float16* As, _Float16* Bs)
{
    const int tid = threadIdx.x;
    const int lane = tid & 63;
    const int w = tid >> 6;
    const int wy = w >> 1, wx = w & 1;
    const int swz = (bid2 & 7) * 64 + (bid2 >> 3);
    const int row0 = (swz >> 2) * 128;
    const int nb = swz & 3;

    floatx4 accA[4][3], accB[4][3];
    #pragma unroll
    for (int a = 0; a < 4; ++a)
        #pragma unroll
        for (int b = 0; b < 3; ++b) {
            accA[a][b] = (floatx4){0.f, 0.f, 0.f, 0.f};
            accB[a][b] = (floatx4){0.f, 0.f, 0.f, 0.f};
        }

    const int slr = lane >> 2;
    const int slc = (lane & 3) * 8;
    const int fr = lane & 15;
    const int fk = (lane >> 4) * 8;

    const int nkt = first ? 8 : 12;
    for (int kt8 = 0; kt8 < nkt; ++kt8) {
        const int kb = kt8 * 32;
        for (int i = w; i < 6; i += 4)
            GLOAD16(WT + (size_t)(nb * 96 + i * 16 + slr) * 384 + kb + slc, &Bs[i * 16 * 32]);
        if (kt8 < 8) {
            #pragma unroll
            for (int i = 0; i < 2; ++i) {
                const int r = w * 32 + i * 16;
                GLOAD16(hx + (size_t)(row0 + r + slr) * 256 + kb + slc, &As[r * 32]);
            }
        } else {
            #pragma unroll
            for (int i = 0; i < 2; ++i) {
                const int r = w * 32 + i * 16;
                GLOAD16(g16_prev + (size_t)(row0 + r + slr) * 128 + (kb - 256) + slc, &As[r * 32]);
            }
        }
        __syncthreads();
        half8 af[4], bf[3];
        #pragma unroll
        for (int mi = 0; mi < 4; ++mi)
            af[mi] = *(const half8*)&As[(wy * 64 + mi * 16 + fr) * 32 + fk];
        #pragma unroll
        for (int ni = 0; ni < 3; ++ni)
            bf[ni] = *(const half8*)&Bs[(wx * 48 + ni * 16 + fr) * 32 + fk];
        if (kt8 < 8) {
            #pragma unroll
            for (int mi = 0; mi < 4; ++mi)
                #pragma unroll
                for (int ni = 0; ni < 3; ++ni)
                    accA[mi][ni] = __builtin_amdgcn_mfma_f32_16x16x32_f16(af[mi], bf[ni], accA[mi][ni], 0, 0, 0);
        } else {
            #pragma unroll
            for (int mi = 0; mi < 4; ++mi)
                #pragma unroll
                for (int ni = 0; ni < 3; ++ni)
                    accB[mi][ni] = __builtin_amdgcn_mfma_f32_16x16x32_f16(af[mi], bf[ni], accB[mi][ni], 0, 0, 0);
        }
        __syncthreads();
    }

    const int U = nb * 32 + wx * 16 + fr;
    const bool uv = U < H2c;
    const float bzi = uv ? b_in[U] : 0.f;
    const float bri = uv ? b_in[H2c + U] : 0.f;
    const float bhi = uv ? b_in[2 * H2c + U] : 0.f;
    const float bzr = uv ? b_rec[U] : 0.f;
    const float brr = uv ? b_rec[H2c + U] : 0.f;
    const float bhr = uv ? b_rec[2 * H2c + U] : 0.f;
    const int rbase = row0 + wy * 64 + (lane >> 4) * 4;
    #pragma unroll
    for (int mi = 0; mi < 4; ++mi) {
        #pragma unroll
        for (int r = 0; r < 4; ++r) {
            const int row = rbase + mi * 16 + r;
            const float gp = (!first && uv) ? g_prev[(size_t)row * H2c + U] : 0.f;
            const float mxz = accA[mi][0][r] + bzi;
            const float mxr = accA[mi][1][r] + bri;
            const float mxh = accA[mi][2][r] + bhi;
            const float mhz = accB[mi][0][r] + bzr;
            const float mhr = accB[mi][1][r] + brr;
            const float mhh = accB[mi][2][r] + bhr;
            const float z = sigm(mxz + mhz);
            const float rr = sigm(mxr + mhr);
            const float hc = fmaxf(mxh + rr * mhh, 0.f);
            const float g = z * gp + (1.f - z) * hc;
            if (uv) g_out[(size_t)row * H2c + U] = g;
            g16_out[(size_t)row * 128 + U] = uv ? (_Float16)g : (_Float16)0.f;
        }
    }
}

// ---------------------------------------------------------------------------
// Fused per-step dispatch: blocks [0,1024) = LSTM(t); blocks [1024,1536) =
// GRU(t-1). GRU(t-1) needs only h_{t-1} and g_{t-2}, both complete before this
// dispatch -> GRU blocks backfill the LSTM occupancy tail (768 blocks/CU-round).
// ---------------------------------------------------------------------------
__global__ __launch_bounds__(256)
void step_fused(const _Float16* __restrict__ xc, const _Float16* __restrict__ WTl,
                const float* __restrict__ b_l,
                const _Float16* __restrict__ h_prev, const float* __restrict__ c_prev,
                _Float16* __restrict__ h_out, float* __restrict__ c_out,
                const _Float16* __restrict__ WTg,
                const float* __restrict__ b_in, const float* __restrict__ b_rec,
                const float* __restrict__ gp_f32, const _Float16* __restrict__ gp_f16,
                float* __restrict__ go_f32, _Float16* __restrict__ go_f16,
                int t, int lstm_first, int gru_first)
{
    __shared__ _Float16 As[128 * 32];
    __shared__ _Float16 Bs[128 * 32];
    const int bid = blockIdx.x;
    if (bid < 1024) {
        lstm_body(bid, xc, WTl, b_l, h_prev, c_prev, h_out, c_out, t, lstm_first, As, Bs);
    } else {
        gru_body(bid - 1024, h_prev, WTg, b_in, b_rec, gp_f32, gp_f16, go_f32, go_f16,
                 gru_first, As, Bs);
    }
}

// Standalone GRU for the final step (t=9).
__global__ __launch_bounds__(256)
void gru_tail(const _Float16* __restrict__ hx, const _Float16* __restrict__ WT,
              const float* __restrict__ b_in, const float* __restrict__ b_rec,
              const float* __restrict__ g_prev, const _Float16* __restrict__ g16_prev,
              float* __restrict__ g_out, _Float16* __restrict__ g16_out)
{
    __shared__ _Float16 As[128 * 32];
    __shared__ _Float16 Bs[128 * 32];
    gru_body(blockIdx.x, hx, WT, b_in, b_rec, g_prev, g16_prev, g_out, g16_out, 0, As, Bs);
}

// ---------------------------------------------------------------------------
// Dense: out = relu(g @ Wd + bd), [B,100]@[100,10]
// ---------------------------------------------------------------------------
__global__ __launch_bounds__(256)
void dense_out(const float* __restrict__ hg, const float* __restrict__ Wd,
               const float* __restrict__ bd, float* __restrict__ out)
{
    __shared__ float wd_s[H2c * TT];
    __shared__ float bd_s[TT];
    const int tid = threadIdx.x;
    for (int i = tid; i < H2c * TT; i += 256) wd_s[i] = Wd[i];
    if (tid < TT) bd_s[tid] = bd[tid];
    __syncthreads();

    const int row = blockIdx.x * 256 + tid;
    float acc[TT];
    #pragma unroll
    for (int j = 0; j < TT; ++j) acc[j] = 0.f;
    const float* hrow = hg + (size_t)row * H2c;
    for (int k = 0; k < H2c; ++k) {
        float xv = hrow[k];
        #pragma unroll
        for (int j = 0; j < TT; ++j) acc[j] += xv * wd_s[k * TT + j];
    }
    #pragma unroll
    for (int j = 0; j < TT; ++j)
        out[(size_t)row * TT + j] = fmaxf(acc[j] + bd_s[j], 0.f);
}

// ---------------------------------------------------------------------------
extern "C" void kernel_launch(void* const* d_in, const int* in_sizes, int n_in,
                              void* d_out, int out_size, void* d_ws, size_t ws_size,
                              hipStream_t stream)
{
    const float* noise  = (const float*)d_in[0];
    const float* Wx_l   = (const float*)d_in[1];
    const float* Wh_l   = (const float*)d_in[2];
    const float* b_l    = (const float*)d_in[3];
    const float* Wx_g   = (const float*)d_in[4];
    const float* Wh_g   = (const float*)d_in[5];
    const float* b_in   = (const float*)d_in[6];
    const float* b_rec  = (const float*)d_in[7];
    const float* Wd     = (const float*)d_in[8];
    const float* bd     = (const float*)d_in[9];
    float* outf = (float*)d_out;

    char* p = (char*)d_ws;
    auto alloc = [&](size_t bytes) {
        char* r = p;
        p += (bytes + 255) & ~(size_t)255;
        return r;
    };
    _Float16* WTl  = (_Float16*)alloc((size_t)1024 * 768 * 2);
    _Float16* WTg  = (_Float16*)alloc((size_t)384 * 384 * 2);
    _Float16* xc   = (_Float16*)alloc((size_t)Bsz * TT * 512 * 2);  // 168 MB
    _Float16* h16A = (_Float16*)alloc((size_t)Bsz * 256 * 2);
    _Float16* h16B = (_Float16*)alloc((size_t)Bsz * 256 * 2);
    float*    cA   = (float*)alloc((size_t)Bsz * 256 * 4);
    float*    cB   = (float*)alloc((size_t)Bsz * 256 * 4);
    float*    gA   = (float*)alloc((size_t)Bsz * 100 * 4);
    float*    gB   = (float*)alloc((size_t)Bsz * 100 * 4);
    _Float16* g16A = (_Float16*)alloc((size_t)Bsz * 128 * 2);
    _Float16* g16B = (_Float16*)alloc((size_t)Bsz * 128 * 2);

    conv_all<<<Bsz * TT * 64 / 256, 256, 0, stream>>>(noise, xc);
    prep_lstm_w<<<1024 * 768 / 256, 256, 0, stream>>>(Wx_l, Wh_l, WTl);
    prep_gru_w<<<(384 * 384 + 255) / 256, 256, 0, stream>>>(Wx_g, Wh_g, WTg);

    _Float16* hb[2] = {h16A, h16B};
    float*    cb[2] = {cA, cB};
    float*    gf[2] = {gA, gB};
    _Float16* gh[2] = {g16A, g16B};

    // t = 0: LSTM only (h0 = c0 = 0); no GRU blocks.
    step_fused<<<1024, 256, 0, stream>>>(
        xc, WTl, b_l, hb[1], cb[1], hb[0], cb[0],
        WTg, b_in, b_rec, gf[0], gh[0], gf[1], gh[1], 0, 1, 0);

    // t = 1..9: LSTM(t) + GRU(t-1) in one dispatch.
    // h[t] in hb[t&1]; g[tau] in gf/gh[tau&1].
    // GRU(t-1): reads g[t-2] = buf[t&1], writes g[t-1] = buf[(t+1)&1].
    for (int t = 1; t < TT; ++t) {
        step_fused<<<1536, 256, 0, stream>>>(
            xc, WTl, b_l, hb[(t - 1) & 1], cb[(t - 1) & 1], hb[t & 1], cb[t & 1],
            WTg, b_in, b_rec, gf[t & 1], gh[t & 1], gf[(t + 1) & 1], gh[(t + 1) & 1],
            t, 0, t == 1 ? 1 : 0);
    }

    // GRU(9): reads h[9] = hb[1], g[8] = buf[0]; writes g[9] = buf[1].
    gru_tail<<<512, 256, 0, stream>>>(hb[1], WTg, b_in, b_rec, gf[0], gh[0], gf[1], gh[1]);
    dense_out<<<Bsz / 256, 256, 0, stream>>>(gf[1], Wd, bd, outf);
}

// Round 5
// 864.461 us; speedup vs baseline: 1.4551x; 1.4551x over previous
//
#include <hip/hip_runtime.h>

#define Bsz 16384
#define TT 10
#define FF 500
#define H1c 256
#define H2c 100

typedef _Float16 half8 __attribute__((ext_vector_type(8)));
typedef float floatx4 __attribute__((ext_vector_type(4)));

__device__ __forceinline__ float sigm(float x) { return 1.0f / (1.0f + __expf(-x)); }

#define GLOAD16(g, l) __builtin_amdgcn_global_load_lds( \
    (const __attribute__((address_space(1))) void*)(g), \
    (__attribute__((address_space(3))) void*)(l), 16, 0, 0)

// ---------------------------------------------------------------------------
// Convert ALL noise fp32 -> xc fp16 once, into t-major planes:
// xc[(t*Bsz + b)*512 + k], 500->512 zero pad. Reads coalesced (noise row
// (b*10+t) is contiguous 500 floats).
// ---------------------------------------------------------------------------
__global__ __launch_bounds__(256)
void conv_all(const float* __restrict__ noise, _Float16* __restrict__ xc)
{
    const int idx = blockIdx.x * 256 + threadIdx.x;   // 163840*64 threads
    const int rb = idx >> 6;           // b*10 + t (noise row)
    const int kc = (idx & 63) << 3;
    const int b = rb / 10;
    const int t = rb - b * 10;
    const float* src = noise + (size_t)rb * FF + kc;
    half8 v;
    if (kc + 8 <= FF) {
        float4 u0 = *(const float4*)src;
        float4 u1 = *(const float4*)(src + 4);
        v[0] = (_Float16)u0.x; v[1] = (_Float16)u0.y; v[2] = (_Float16)u0.z; v[3] = (_Float16)u0.w;
        v[4] = (_Float16)u1.x; v[5] = (_Float16)u1.y; v[6] = (_Float16)u1.z; v[7] = (_Float16)u1.w;
    } else {
        #pragma unroll
        for (int j = 0; j < 8; ++j)
            v[j] = (kc + j < FF) ? (_Float16)src[j] : (_Float16)0.f;
    }
    *(half8*)(xc + ((size_t)t * Bsz + b) * 512 + kc) = v;
}

// ---------------------------------------------------------------------------
// LSTM weight prep (K=768): n' = 128*(U>>5)+64*((U>>4)&1)+16*g+(U&15)
// k<512: Wx rows (500 real, pad 0); k in [512,768): Wh rows.
// ---------------------------------------------------------------------------
__global__ __launch_bounds__(256)
void prep_lstm_w(const float* __restrict__ Wx, const float* __restrict__ Wh,
                 _Float16* __restrict__ WT)
{
    const int idx = blockIdx.x * 256 + threadIdx.x;   // 1024*768
    const int np = idx / 768, k = idx % 768;
    const int a = np >> 7, b2 = (np >> 6) & 1, g = (np >> 4) & 3, u = np & 15;
    const int U = a * 32 + b2 * 16 + u;
    const int col = g * 256 + U;
    float v = 0.f;
    if (k < 512) { if (k < FF) v = Wx[(size_t)k * 1024 + col]; }
    else v = Wh[(size_t)(k - 512) * 1024 + col];
    WT[idx] = (_Float16)v;
}

// ---------------------------------------------------------------------------
// GRU weight prep: n' = 96*(U>>5)+48*((U>>4)&1)+16*g+(U&15), U in [0,128).
// k<256: Wxg rows; k in [256,384): Whg rows (100 real).
// ---------------------------------------------------------------------------
__global__ __launch_bounds__(256)
void prep_gru_w(const float* __restrict__ Wxg, const float* __restrict__ Whg,
                _Float16* __restrict__ WT)
{
    const int idx = blockIdx.x * 256 + threadIdx.x;   // 384*384
    if (idx >= 384 * 384) return;
    const int np = idx / 384, k = idx % 384;
    const int nb = np / 96, rem = np % 96;
    const int wxx = rem / 48, g = (rem % 48) / 16, u = rem & 15;
    const int U = nb * 32 + wxx * 16 + u;
    float v = 0.f;
    if (U < H2c) {
        if (k < 256) v = Wxg[(size_t)k * 300 + g * H2c + U];
        else if (k - 256 < H2c) v = Whg[(size_t)(k - 256) * 300 + g * H2c + U];
    }
    WT[idx] = (_Float16)v;
}

// ---------------------------------------------------------------------------
// LSTM step via MFMA, K=768 fused. 128x128 tile, 4 waves, BK=32, grid(128,8).
// LDS chunk swizzle (both-sides XOR involution within each 16-row gload tile):
//   LDS(r, q') holds global chunk (r, q' ^ ((r>>1)&3)); gload source uses
//   q_src = (lane&3) ^ ((lane>>3)&3); frag reads use q' = q ^ ((fr>>1)&3).
// -> each 8-lane LDS service group covers all 32 banks (conflict-free).
// ---------------------------------------------------------------------------
__global__ __launch_bounds__(256)
void lstm_mfma(const _Float16* __restrict__ xct, const _Float16* __restrict__ WT,
               const float* __restrict__ bias,
               const _Float16* __restrict__ h_prev, const float* __restrict__ c_prev,
               _Float16* __restrict__ h_out, float* __restrict__ c_out, int first)
{
    __shared__ _Float16 As[128 * 32];
    __shared__ _Float16 Bs[128 * 32];

    const int tid = threadIdx.x;
    const int lane = tid & 63;
    const int w = tid >> 6;
    const int wy = w >> 1, wx = w & 1;
    const int row0 = blockIdx.x * 128;
    const int nb = blockIdx.y;

    floatx4 acc[4][4];
    #pragma unroll
    for (int a = 0; a < 4; ++a)
        #pragma unroll
        for (int b = 0; b < 4; ++b) acc[a][b] = (floatx4){0.f, 0.f, 0.f, 0.f};

    const int slr = lane >> 2;                                   // row in 16-row tile
    const int slc = (((lane & 3) ^ ((lane >> 3) & 3)) << 3);     // swizzled src chunk (halves)
    const int fr = lane & 15;
    const int fq = (((lane >> 4) ^ ((fr >> 1) & 3)) << 3);       // swizzled read chunk (halves)

    const int nkt = first ? 16 : 24;
    for (int kt8 = 0; kt8 < nkt; ++kt8) {
        const int kb = kt8 * 32;
        #pragma unroll
        for (int i = 0; i < 2; ++i) {
            const int r = w * 32 + i * 16;
            GLOAD16(WT + (size_t)(nb * 128 + r + slr) * 768 + kb + slc, &Bs[r * 32]);
        }
        if (kt8 < 16) {
            #pragma unroll
            for (int i = 0; i < 2; ++i) {
                const int r = w * 32 + i * 16;
                GLOAD16(xct + (size_t)(row0 + r + slr) * 512 + kb + slc, &As[r * 32]);
            }
        } else {
            #pragma unroll
            for (int i = 0; i < 2; ++i) {
                const int r = w * 32 + i * 16;
                GLOAD16(h_prev + (size_t)(row0 + r + slr) * 256 + (kb - 512) + slc, &As[r * 32]);
            }
        }
        __syncthreads();
        half8 af[4], bf[4];
        #pragma unroll
        for (int mi = 0; mi < 4; ++mi)
            af[mi] = *(const half8*)&As[(wy * 64 + mi * 16 + fr) * 32 + fq];
        #pragma unroll
        for (int ni = 0; ni < 4; ++ni)
            bf[ni] = *(const half8*)&Bs[(wx * 64 + ni * 16 + fr) * 32 + fq];
        #pragma unroll
        for (int mi = 0; mi < 4; ++mi)
            #pragma unroll
            for (int ni = 0; ni < 4; ++ni)
                acc[mi][ni] = __builtin_amdgcn_mfma_f32_16x16x32_f16(af[mi], bf[ni], acc[mi][ni], 0, 0, 0);
        __syncthreads();
    }

    const int U = nb * 32 + wx * 16 + fr;
    const float bi = bias[0 * 256 + U];
    const float bff = bias[1 * 256 + U];
    const float bg = bias[2 * 256 + U];
    const float bo = bias[3 * 256 + U];
    const int rbase = row0 + wy * 64 + (lane >> 4) * 4;
    #pragma unroll
    for (int mi = 0; mi < 4; ++mi) {
        #pragma unroll
        for (int r = 0; r < 4; ++r) {
            const int row = rbase + mi * 16 + r;
            const float cp = first ? 0.f : c_prev[(size_t)row * 256 + U];
            const float zi = acc[mi][0][r] + bi;
            const float zf = acc[mi][1][r] + bff;
            const float zg = acc[mi][2][r] + bg;
            const float zo = acc[mi][3][r] + bo;
            const float ig = sigm(zi), fg = sigm(zf), og = sigm(zo);
            const float gg = fmaxf(zg, 0.f);
            const float cv = fg * cp + ig * gg;
            const float hv = og * fmaxf(cv, 0.f);
            c_out[(size_t)row * 256 + U] = cv;
            h_out[(size_t)row * 256 + U] = (_Float16)hv;
        }
    }
}

// ---------------------------------------------------------------------------
// GRU step via MFMA. mx = h @ Wxg (K=256), mh = g_prev @ Whg (K=128 padded).
// 128x96 tile (3 gates x 32 units), 4 waves, grid(128,4). Same LDS swizzle.
// ---------------------------------------------------------------------------
__global__ __launch_bounds__(256)
void gru_mfma(const _Float16* __restrict__ hx, const _Float16* __restrict__ WT,
              const float* __restrict__ b_in, const float* __restrict__ b_rec,
              const float* __restrict__ g_prev, const _Float16* __restrict__ g16_prev,
              float* __restrict__ g_out, _Float16* __restrict__ g16_out, int first)
{
    __shared__ _Float16 As[128 * 32];
    __shared__ _Float16 Bs[96 * 32];

    const int tid = threadIdx.x;
    const int lane = tid & 63;
    const int w = tid >> 6;
    const int wy = w >> 1, wx = w & 1;
    const int row0 = blockIdx.x * 128;
    const int nb = blockIdx.y;

    floatx4 accA[4][3], accB[4][3];
    #pragma unroll
    for (int a = 0; a < 4; ++a)
        #pragma unroll
        for (int b = 0; b < 3; ++b) {
            accA[a][b] = (floatx4){0.f, 0.f, 0.f, 0.f};
            accB[a][b] = (floatx4){0.f, 0.f, 0.f, 0.f};
        }

    const int slr = lane >> 2;
    const int slc = (((lane & 3) ^ ((lane >> 3) & 3)) << 3);
    const int fr = lane & 15;
    const int fq = (((lane >> 4) ^ ((fr >> 1) & 3)) << 3);

    const int nkt = first ? 8 : 12;
    for (int kt8 = 0; kt8 < nkt; ++kt8) {
        const int kb = kt8 * 32;
        for (int i = w; i < 6; i += 4)
            GLOAD16(WT + (size_t)(nb * 96 + i * 16 + slr) * 384 + kb + slc, &Bs[i * 16 * 32]);
        if (kt8 < 8) {
            #pragma unroll
            for (int i = 0; i < 2; ++i) {
                const int r = w * 32 + i * 16;
                GLOAD16(hx + (size_t)(row0 + r + slr) * 256 + kb + slc, &As[r * 32]);
            }
        } else {
            #pragma unroll
            for (int i = 0; i < 2; ++i) {
                const int r = w * 32 + i * 16;
                GLOAD16(g16_prev + (size_t)(row0 + r + slr) * 128 + (kb - 256) + slc, &As[r * 32]);
            }
        }
        __syncthreads();
        half8 af[4], bf[3];
        #pragma unroll
        for (int mi = 0; mi < 4; ++mi)
            af[mi] = *(const half8*)&As[(wy * 64 + mi * 16 + fr) * 32 + fq];
        #pragma unroll
        for (int ni = 0; ni < 3; ++ni)
            bf[ni] = *(const half8*)&Bs[(wx * 48 + ni * 16 + fr) * 32 + fq];
        if (kt8 < 8) {
            #pragma unroll
            for (int mi = 0; mi < 4; ++mi)
                #pragma unroll
                for (int ni = 0; ni < 3; ++ni)
                    accA[mi][ni] = __builtin_amdgcn_mfma_f32_16x16x32_f16(af[mi], bf[ni], accA[mi][ni], 0, 0, 0);
        } else {
            #pragma unroll
            for (int mi = 0; mi < 4; ++mi)
                #pragma unroll
                for (int ni = 0; ni < 3; ++ni)
                    accB[mi][ni] = __builtin_amdgcn_mfma_f32_16x16x32_f16(af[mi], bf[ni], accB[mi][ni], 0, 0, 0);
        }
        __syncthreads();
    }

    const int U = nb * 32 + wx * 16 + fr;
    const bool uv = U < H2c;
    const float bzi = uv ? b_in[U] : 0.f;
    const float bri = uv ? b_in[H2c + U] : 0.f;
    const float bhi = uv ? b_in[2 * H2c + U] : 0.f;
    const float bzr = uv ? b_rec[U] : 0.f;
    const float brr = uv ? b_rec[H2c + U] : 0.f;
    const float bhr = uv ? b_rec[2 * H2c + U] : 0.f;
    const int rbase = row0 + wy * 64 + (lane >> 4) * 4;
    #pragma unroll
    for (int mi = 0; mi < 4; ++mi) {
        #pragma unroll
        for (int r = 0; r < 4; ++r) {
            const int row = rbase + mi * 16 + r;
            const float gp = (!first && uv) ? g_prev[(size_t)row * H2c + U] : 0.f;
            const float mxz = accA[mi][0][r] + bzi;
            const float mxr = accA[mi][1][r] + bri;
            const float mxh = accA[mi][2][r] + bhi;
            const float mhz = accB[mi][0][r] + bzr;
            const float mhr = accB[mi][1][r] + brr;
            const float mhh = accB[mi][2][r] + bhr;
            const float z = sigm(mxz + mhz);
            const float rr = sigm(mxr + mhr);
            const float hc = fmaxf(mxh + rr * mhh, 0.f);
            const float g = z * gp + (1.f - z) * hc;
            if (uv) g_out[(size_t)row * H2c + U] = g;
            g16_out[(size_t)row * 128 + U] = uv ? (_Float16)g : (_Float16)0.f;
        }
    }
}

// ---------------------------------------------------------------------------
// Dense: out = relu(g @ Wd + bd), [B,100]@[100,10]
// ---------------------------------------------------------------------------
__global__ __launch_bounds__(256)
void dense_out(const float* __restrict__ hg, const float* __restrict__ Wd,
               const float* __restrict__ bd, float* __restrict__ out)
{
    __shared__ float wd_s[H2c * TT];
    __shared__ float bd_s[TT];
    const int tid = threadIdx.x;
    for (int i = tid; i < H2c * TT; i += 256) wd_s[i] = Wd[i];
    if (tid < TT) bd_s[tid] = bd[tid];
    __syncthreads();

    const int row = blockIdx.x * 256 + tid;
    float acc[TT];
    #pragma unroll
    for (int j = 0; j < TT; ++j) acc[j] = 0.f;
    const float* hrow = hg + (size_t)row * H2c;
    for (int k = 0; k < H2c; ++k) {
        float xv = hrow[k];
        #pragma unroll
        for (int j = 0; j < TT; ++j) acc[j] += xv * wd_s[k * TT + j];
    }
    #pragma unroll
    for (int j = 0; j < TT; ++j)
        out[(size_t)row * TT + j] = fmaxf(acc[j] + bd_s[j], 0.f);
}

// ---------------------------------------------------------------------------
extern "C" void kernel_launch(void* const* d_in, const int* in_sizes, int n_in,
                              void* d_out, int out_size, void* d_ws, size_t ws_size,
                              hipStream_t stream)
{
    const float* noise  = (const float*)d_in[0];
    const float* Wx_l   = (const float*)d_in[1];
    const float* Wh_l   = (const float*)d_in[2];
    const float* b_l    = (const float*)d_in[3];
    const float* Wx_g   = (const float*)d_in[4];
    const float* Wh_g   = (const float*)d_in[5];
    const float* b_in   = (const float*)d_in[6];
    const float* b_rec  = (const float*)d_in[7];
    const float* Wd     = (const float*)d_in[8];
    const float* bd     = (const float*)d_in[9];
    float* outf = (float*)d_out;

    char* p = (char*)d_ws;
    auto alloc = [&](size_t bytes) {
        char* r = p;
        p += (bytes + 255) & ~(size_t)255;
        return r;
    };
    _Float16* WTl  = (_Float16*)alloc((size_t)1024 * 768 * 2);
    _Float16* WTg  = (_Float16*)alloc((size_t)384 * 384 * 2);
    _Float16* xc   = (_Float16*)alloc((size_t)Bsz * TT * 512 * 2);  // 168 MB
    _Float16* h16A = (_Float16*)alloc((size_t)Bsz * 256 * 2);
    _Float16* h16B = (_Float16*)alloc((size_t)Bsz * 256 * 2);
    float*    cA   = (float*)alloc((size_t)Bsz * 256 * 4);
    float*    cB   = (float*)alloc((size_t)Bsz * 256 * 4);
    float*    gA   = (float*)alloc((size_t)Bsz * 100 * 4);
    float*    gB   = (float*)alloc((size_t)Bsz * 100 * 4);
    _Float16* g16A = (_Float16*)alloc((size_t)Bsz * 128 * 2);
    _Float16* g16B = (_Float16*)alloc((size_t)Bsz * 128 * 2);

    conv_all<<<Bsz * TT * 64 / 256, 256, 0, stream>>>(noise, xc);
    prep_lstm_w<<<1024 * 768 / 256, 256, 0, stream>>>(Wx_l, Wh_l, WTl);
    prep_gru_w<<<(384 * 384 + 255) / 256, 256, 0, stream>>>(Wx_g, Wh_g, WTg);

    _Float16 *h_r = h16B, *h_w = h16A;
    float *c_r = cB, *c_w = cA;
    float *g_r = gB, *g_w = gA;
    _Float16 *g16_r = g16B, *g16_w = g16A;
    float* g_last = gA;

    for (int t = 0; t < TT; ++t) {
        lstm_mfma<<<dim3(128, 8), 256, 0, stream>>>(
            xc + (size_t)t * Bsz * 512, WTl, b_l, h_r, c_r, h_w, c_w, t == 0 ? 1 : 0);
        gru_mfma<<<dim3(128, 4), 256, 0, stream>>>(
            h_w, WTg, b_in, b_rec, g_r, g16_r, g_w, g16_w, t == 0 ? 1 : 0);
        g_last = g_w;
        _Float16* th;
        float* tf;
        th = h_r; h_r = h_w; h_w = th;
        tf = c_r; c_r = c_w; c_w = tf;
        tf = g_r; g_r = g_w; g_w = tf;
        th = g16_r; g16_r = g16_w; g16_w = th;
    }
    dense_out<<<Bsz / 256, 256, 0, stream>>>(g_last, Wd, bd, outf);
}

// Round 6
// 764.693 us; speedup vs baseline: 1.6450x; 1.1305x over previous
//
#include <hip/hip_runtime.h>

#define Bsz 16384
#define TT 10
#define FF 500
#define H1c 256
#define H2c 100

typedef _Float16 half8 __attribute__((ext_vector_type(8)));
typedef float floatx4 __attribute__((ext_vector_type(4)));

__device__ __forceinline__ float sigm(float x) { return 1.0f / (1.0f + __expf(-x)); }

#define GLOAD16(g, l) __builtin_amdgcn_global_load_lds( \
    (const __attribute__((address_space(1))) void*)(g), \
    (__attribute__((address_space(3))) void*)(l), 16, 0, 0)

// ---------------------------------------------------------------------------
// Convert ALL noise fp32 -> xc fp16 once, into t-major planes:
// xc[(t*Bsz + b)*512 + k], 500->512 zero pad.
// ---------------------------------------------------------------------------
__global__ __launch_bounds__(256)
void conv_all(const float* __restrict__ noise, _Float16* __restrict__ xc)
{
    const int idx = blockIdx.x * 256 + threadIdx.x;
    const int rb = idx >> 6;           // b*10 + t (noise row)
    const int kc = (idx & 63) << 3;
    const int b = rb / 10;
    const int t = rb - b * 10;
    const float* src = noise + (size_t)rb * FF + kc;
    half8 v;
    if (kc + 8 <= FF) {
        float4 u0 = *(const float4*)src;
        float4 u1 = *(const float4*)(src + 4);
        v[0] = (_Float16)u0.x; v[1] = (_Float16)u0.y; v[2] = (_Float16)u0.z; v[3] = (_Float16)u0.w;
        v[4] = (_Float16)u1.x; v[5] = (_Float16)u1.y; v[6] = (_Float16)u1.z; v[7] = (_Float16)u1.w;
    } else {
        #pragma unroll
        for (int j = 0; j < 8; ++j)
            v[j] = (kc + j < FF) ? (_Float16)src[j] : (_Float16)0.f;
    }
    *(half8*)(xc + ((size_t)t * Bsz + b) * 512 + kc) = v;
}

// ---------------------------------------------------------------------------
// LSTM weight prep (K=768) for 256-wide N-tiles:
// n' = 256*(U>>6) + 64*((U>>4)&3) + 16*g + (U&15)
// k<512: Wx rows (500 real, pad 0); k in [512,768): Wh rows.
// ---------------------------------------------------------------------------
__global__ __launch_bounds__(256)
void prep_lstm_w(const float* __restrict__ Wx, const float* __restrict__ Wh,
                 _Float16* __restrict__ WT)
{
    const int idx = blockIdx.x * 256 + threadIdx.x;   // 1024*768
    const int np = idx / 768, k = idx % 768;
    const int A2 = np >> 8, B2 = (np >> 6) & 3, g = (np >> 4) & 3, u = np & 15;
    const int U = A2 * 64 + B2 * 16 + u;
    const int col = g * 256 + U;
    float v = 0.f;
    if (k < 512) { if (k < FF) v = Wx[(size_t)k * 1024 + col]; }
    else v = Wh[(size_t)(k - 512) * 1024 + col];
    WT[idx] = (_Float16)v;
}

// ---------------------------------------------------------------------------
// GRU weight prep: n' = 96*(U>>5)+48*((U>>4)&1)+16*g+(U&15), U in [0,128).
// ---------------------------------------------------------------------------
__global__ __launch_bounds__(256)
void prep_gru_w(const float* __restrict__ Wxg, const float* __restrict__ Whg,
                _Float16* __restrict__ WT)
{
    const int idx = blockIdx.x * 256 + threadIdx.x;   // 384*384
    if (idx >= 384 * 384) return;
    const int np = idx / 384, k = idx % 384;
    const int nb = np / 96, rem = np % 96;
    const int wxx = rem / 48, g = (rem % 48) / 16, u = rem & 15;
    const int U = nb * 32 + wxx * 16 + u;
    float v = 0.f;
    if (U < H2c) {
        if (k < 256) v = Wxg[(size_t)k * 300 + g * H2c + U];
        else if (k - 256 < H2c) v = Whg[(size_t)(k - 256) * 300 + g * H2c + U];
    }
    WT[idx] = (_Float16)v;
}

// ---------------------------------------------------------------------------
// LSTM step, 256x256 tile, 8 waves (2x4), BK=64, double-buffered 128 KiB LDS.
// Per K-tile: 4 quadrant-phases of {12 ds_read || 2 global_load_lds || 16 MFMA},
// one __syncthreads per K-tile. XOR chunk swizzle (chunk ^= row&7, involution)
// applied on the global source AND the ds_read address (LDS stays linear for
// global_load_lds). grid(256) = 1 block/CU, XCD-swizzled.
// ---------------------------------------------------------------------------
__global__ __launch_bounds__(512, 2)
void lstm_mfma256(const _Float16* __restrict__ xct, const _Float16* __restrict__ WT,
                  const float* __restrict__ bias,
                  const _Float16* __restrict__ h_prev, const float* __restrict__ c_prev,
                  _Float16* __restrict__ h_out, float* __restrict__ c_out, int first)
{
    extern __shared__ _Float16 smem[];      // As[2][256][64] then Bs[2][256][64]
    _Float16* As = smem;
    _Float16* Bs = smem + 32768;

    const int tid = threadIdx.x;
    const int lane = tid & 63;
    const int w = tid >> 6;                 // 0..7
    const int wy = w >> 2, wx = w & 3;
    const int bid = blockIdx.x;
    const int swz = (bid & 7) * 32 + (bid >> 3);
    const int row0 = (swz >> 2) * 256;
    const int nb = swz & 3;

    const int fr = lane & 15;
    const int l4 = lane >> 4;               // 0..3
    const int sr8 = lane >> 3;              // 0..7 (row within 8-row slab)
    const int qsrc = (((lane & 7) ^ (sr8 & 7)) << 3);   // swizzled src chunk (halves)

    floatx4 acc[8][4];
    #pragma unroll
    for (int a = 0; a < 8; ++a)
        #pragma unroll
        for (int b = 0; b < 4; ++b) acc[a][b] = (floatx4){0.f, 0.f, 0.f, 0.f};

    const int nkt = first ? 8 : 12;

    // prologue: stage K-tile 0 (kb=0 -> A from xct)
    #pragma unroll
    for (int q = 0; q < 4; ++q) {
        const int r = q * 64 + w * 8;
        GLOAD16(xct + (size_t)(row0 + r + sr8) * 512 + qsrc, &As[r * 64]);
        GLOAD16(WT + (size_t)(nb * 256 + r + sr8) * 768 + qsrc, &Bs[r * 64]);
    }
    __syncthreads();

    for (int T = 0; T < nkt; ++T) {
        const int pbase = (T & 1) * 16384;
        const int sbase = pbase ^ 16384;
        const int kb2 = (T + 1) * 64;
        const bool do_stage = (T + 1 < nkt);
        const bool from_x = kb2 < 512;

        #pragma unroll
        for (int q = 0; q < 4; ++q) {
            const int mh = q >> 1, nh = q & 1;
            half8 af[4][2], bf[2][2];
            #pragma unroll
            for (int j = 0; j < 4; ++j) {
                const int row = wy * 128 + (mh * 4 + j) * 16 + fr;
                #pragma unroll
                for (int ks = 0; ks < 2; ++ks) {
                    const int ch = (ks * 4 + l4) ^ (fr & 7);
                    af[j][ks] = *(const half8*)&As[pbase + row * 64 + ch * 8];
                }
            }
            #pragma unroll
            for (int jn = 0; jn < 2; ++jn) {
                const int row = wx * 64 + (nh * 2 + jn) * 16 + fr;
                #pragma unroll
                for (int ks = 0; ks < 2; ++ks) {
                    const int ch = (ks * 4 + l4) ^ (fr & 7);
                    bf[jn][ks] = *(const half8*)&Bs[pbase + row * 64 + ch * 8];
                }
            }
            if (do_stage) {
                const int r = q * 64 + w * 8;
                if (from_x)
                    GLOAD16(xct + (size_t)(row0 + r + sr8) * 512 + kb2 + qsrc, &As[sbase + r * 64]);
                else
                    GLOAD16(h_prev + (size_t)(row0 + r + sr8) * 256 + (kb2 - 512) + qsrc, &As[sbase + r * 64]);
                GLOAD16(WT + (size_t)(nb * 256 + r + sr8) * 768 + kb2 + qsrc, &Bs[sbase + r * 64]);
            }
            __builtin_amdgcn_s_setprio(1);
            #pragma unroll
            for (int ks = 0; ks < 2; ++ks)
                #pragma unroll
                for (int j = 0; j < 4; ++j)
                    #pragma unroll
                    for (int jn = 0; jn < 2; ++jn)
                        acc[mh * 4 + j][nh * 2 + jn] = __builtin_amdgcn_mfma_f32_16x16x32_f16(
                            af[j][ks], bf[jn][ks], acc[mh * 4 + j][nh * 2 + jn], 0, 0, 0);
            __builtin_amdgcn_s_setprio(0);
            __builtin_amdgcn_sched_barrier(0);
        }
        __syncthreads();
    }

    // epilogue: lane owns unit U, gates = ni fragments
    const int U = nb * 64 + wx * 16 + fr;
    const float bi = bias[0 * 256 + U];
    const float bff = bias[1 * 256 + U];
    const float bg = bias[2 * 256 + U];
    const float bo = bias[3 * 256 + U];
    const int rbase = row0 + wy * 128 + l4 * 4;
    #pragma unroll
    for (int mi = 0; mi < 8; ++mi) {
        #pragma unroll
        for (int r = 0; r < 4; ++r) {
            const int row = rbase + mi * 16 + r;
            const float cp = first ? 0.f : c_prev[(size_t)row * 256 + U];
            const float zi = acc[mi][0][r] + bi;
            const float zf = acc[mi][1][r] + bff;
            const float zg = acc[mi][2][r] + bg;
            const float zo = acc[mi][3][r] + bo;
            const float ig = sigm(zi), fg = sigm(zf), og = sigm(zo);
            const float gg = fmaxf(zg, 0.f);
            const float cv = fg * cp + ig * gg;
            const float hv = og * fmaxf(cv, 0.f);
            c_out[(size_t)row * 256 + U] = cv;
            h_out[(size_t)row * 256 + U] = (_Float16)hv;
        }
    }
}

// ---------------------------------------------------------------------------
// GRU step via MFMA (unchanged from r5). 128x96 tile, 4 waves, grid(128,4).
// ---------------------------------------------------------------------------
__global__ __launch_bounds__(256)
void gru_mfma(const _Float16* __restrict__ hx, const _Float16* __restrict__ WT,
              const float* __restrict__ b_in, const float* __restrict__ b_rec,
              const float* __restrict__ g_prev, const _Float16* __restrict__ g16_prev,
              float* __restrict__ g_out, _Float16* __restrict__ g16_out, int first)
{
    __shared__ _Float16 As[128 * 32];
    __shared__ _Float16 Bs[96 * 32];

    const int tid = threadIdx.x;
    const int lane = tid & 63;
    const int w = tid >> 6;
    const int wy = w >> 1, wx = w & 1;
    const int row0 = blockIdx.x * 128;
    const int nb = blockIdx.y;

    floatx4 accA[4][3], accB[4][3];
    #pragma unroll
    for (int a = 0; a < 4; ++a)
        #pragma unroll
        for (int b = 0; b < 3; ++b) {
            accA[a][b] = (floatx4){0.f, 0.f, 0.f, 0.f};
            accB[a][b] = (floatx4){0.f, 0.f, 0.f, 0.f};
        }

    const int slr = lane >> 2;
    const int slc = (((lane & 3) ^ ((lane >> 3) & 3)) << 3);
    const int fr = lane & 15;
    const int fq = (((lane >> 4) ^ ((fr >> 1) & 3)) << 3);

    const int nkt = first ? 8 : 12;
    for (int kt8 = 0; kt8 < nkt; ++kt8) {
        const int kb = kt8 * 32;
        for (int i = w; i < 6; i += 4)
            GLOAD16(WT + (size_t)(nb * 96 + i * 16 + slr) * 384 + kb + slc, &Bs[i * 16 * 32]);
        if (kt8 < 8) {
            #pragma unroll
            for (int i = 0; i < 2; ++i) {
                const int r = w * 32 + i * 16;
                GLOAD16(hx + (size_t)(row0 + r + slr) * 256 + kb + slc, &As[r * 32]);
            }
        } else {
            #pragma unroll
            for (int i = 0; i < 2; ++i) {
                const int r = w * 32 + i * 16;
                GLOAD16(g16_prev + (size_t)(row0 + r + slr) * 128 + (kb - 256) + slc, &As[r * 32]);
            }
        }
        __syncthreads();
        half8 af[4], bf[3];
        #pragma unroll
        for (int mi = 0; mi < 4; ++mi)
            af[mi] = *(const half8*)&As[(wy * 64 + mi * 16 + fr) * 32 + fq];
        #pragma unroll
        for (int ni = 0; ni < 3; ++ni)
            bf[ni] = *(const half8*)&Bs[(wx * 48 + ni * 16 + fr) * 32 + fq];
        if (kt8 < 8) {
            #pragma unroll
            for (int mi = 0; mi < 4; ++mi)
                #pragma unroll
                for (int ni = 0; ni < 3; ++ni)
                    accA[mi][ni] = __builtin_amdgcn_mfma_f32_16x16x32_f16(af[mi], bf[ni], accA[mi][ni], 0, 0, 0);
        } else {
            #pragma unroll
            for (int mi = 0; mi < 4; ++mi)
                #pragma unroll
                for (int ni = 0; ni < 3; ++ni)
                    accB[mi][ni] = __builtin_amdgcn_mfma_f32_16x16x32_f16(af[mi], bf[ni], accB[mi][ni], 0, 0, 0);
        }
        __syncthreads();
    }

    const int U = nb * 32 + wx * 16 + fr;
    const bool uv = U < H2c;
    const float bzi = uv ? b_in[U] : 0.f;
    const float bri = uv ? b_in[H2c + U] : 0.f;
    const float bhi = uv ? b_in[2 * H2c + U] : 0.f;
    const float bzr = uv ? b_rec[U] : 0.f;
    const float brr = uv ? b_rec[H2c + U] : 0.f;
    const float bhr = uv ? b_rec[2 * H2c + U] : 0.f;
    const int rbase = row0 + wy * 64 + (lane >> 4) * 4;
    #pragma unroll
    for (int mi = 0; mi < 4; ++mi) {
        #pragma unroll
        for (int r = 0; r < 4; ++r) {
            const int row = rbase + mi * 16 + r;
            const float gp = (!first && uv) ? g_prev[(size_t)row * H2c + U] : 0.f;
            const float mxz = accA[mi][0][r] + bzi;
            const float mxr = accA[mi][1][r] + bri;
            const float mxh = accA[mi][2][r] + bhi;
            const float mhz = accB[mi][0][r] + bzr;
            const float mhr = accB[mi][1][r] + brr;
            const float mhh = accB[mi][2][r] + bhr;
            const float z = sigm(mxz + mhz);
            const float rr = sigm(mxr + mhr);
            const float hc = fmaxf(mxh + rr * mhh, 0.f);
            const float g = z * gp + (1.f - z) * hc;
            if (uv) g_out[(size_t)row * H2c + U] = g;
            g16_out[(size_t)row * 128 + U] = uv ? (_Float16)g : (_Float16)0.f;
        }
    }
}

// ---------------------------------------------------------------------------
// Dense: out = relu(g @ Wd + bd), [B,100]@[100,10]
// ---------------------------------------------------------------------------
__global__ __launch_bounds__(256)
void dense_out(const float* __restrict__ hg, const float* __restrict__ Wd,
               const float* __restrict__ bd, float* __restrict__ out)
{
    __shared__ float wd_s[H2c * TT];
    __shared__ float bd_s[TT];
    const int tid = threadIdx.x;
    for (int i = tid; i < H2c * TT; i += 256) wd_s[i] = Wd[i];
    if (tid < TT) bd_s[tid] = bd[tid];
    __syncthreads();

    const int row = blockIdx.x * 256 + tid;
    float acc[TT];
    #pragma unroll
    for (int j = 0; j < TT; ++j) acc[j] = 0.f;
    const float* hrow = hg + (size_t)row * H2c;
    for (int k = 0; k < H2c; ++k) {
        float xv = hrow[k];
        #pragma unroll
        for (int j = 0; j < TT; ++j) acc[j] += xv * wd_s[k * TT + j];
    }
    #pragma unroll
    for (int j = 0; j < TT; ++j)
        out[(size_t)row * TT + j] = fmaxf(acc[j] + bd_s[j], 0.f);
}

// ---------------------------------------------------------------------------
extern "C" void kernel_launch(void* const* d_in, const int* in_sizes, int n_in,
                              void* d_out, int out_size, void* d_ws, size_t ws_size,
                              hipStream_t stream)
{
    const float* noise  = (const float*)d_in[0];
    const float* Wx_l   = (const float*)d_in[1];
    const float* Wh_l   = (const float*)d_in[2];
    const float* b_l    = (const float*)d_in[3];
    const float* Wx_g   = (const float*)d_in[4];
    const float* Wh_g   = (const float*)d_in[5];
    const float* b_in   = (const float*)d_in[6];
    const float* b_rec  = (const float*)d_in[7];
    const float* Wd     = (const float*)d_in[8];
    const float* bd     = (const float*)d_in[9];
    float* outf = (float*)d_out;

    char* p = (char*)d_ws;
    auto alloc = [&](size_t bytes) {
        char* r = p;
        p += (bytes + 255) & ~(size_t)255;
        return r;
    };
    _Float16* WTl  = (_Float16*)alloc((size_t)1024 * 768 * 2);
    _Float16* WTg  = (_Float16*)alloc((size_t)384 * 384 * 2);
    _Float16* xc   = (_Float16*)alloc((size_t)Bsz * TT * 512 * 2);  // 168 MB
    _Float16* h16A = (_Float16*)alloc((size_t)Bsz * 256 * 2);
    _Float16* h16B = (_Float16*)alloc((size_t)Bsz * 256 * 2);
    float*    cA   = (float*)alloc((size_t)Bsz * 256 * 4);
    float*    cB   = (float*)alloc((size_t)Bsz * 256 * 4);
    float*    gA   = (float*)alloc((size_t)Bsz * 100 * 4);
    float*    gB   = (float*)alloc((size_t)Bsz * 100 * 4);
    _Float16* g16A = (_Float16*)alloc((size_t)Bsz * 128 * 2);
    _Float16* g16B = (_Float16*)alloc((size_t)Bsz * 128 * 2);

    (void)hipFuncSetAttribute((const void*)lstm_mfma256,
                              hipFuncAttributeMaxDynamicSharedMemorySize, 131072);

    conv_all<<<Bsz * TT * 64 / 256, 256, 0, stream>>>(noise, xc);
    prep_lstm_w<<<1024 * 768 / 256, 256, 0, stream>>>(Wx_l, Wh_l, WTl);
    prep_gru_w<<<(384 * 384 + 255) / 256, 256, 0, stream>>>(Wx_g, Wh_g, WTg);

    _Float16 *h_r = h16B, *h_w = h16A;
    float *c_r = cB, *c_w = cA;
    float *g_r = gB, *g_w = gA;
    _Float16 *g16_r = g16B, *g16_w = g16A;
    float* g_last = gA;

    for (int t = 0; t < TT; ++t) {
        lstm_mfma256<<<256, 512, 131072, stream>>>(
            xc + (size_t)t * Bsz * 512, WTl, b_l, h_r, c_r, h_w, c_w, t == 0 ? 1 : 0);
        gru_mfma<<<dim3(128, 4), 256, 0, stream>>>(
            h_w, WTg, b_in, b_rec, g_r, g16_r, g_w, g16_w, t == 0 ? 1 : 0);
        g_last = g_w;
        _Float16* th;
        float* tf;
        th = h_r; h_r = h_w; h_w = th;
        tf = c_r; c_r = c_w; c_w = tf;
        tf = g_r; g_r = g_w; g_w = tf;
        th = g16_r; g16_r = g16_w; g16_w = th;
    }
    dense_out<<<Bsz / 256, 256, 0, stream>>>(g_last, Wd, bd, outf);
}